// Round 1
// baseline (668.606 us; speedup 1.0000x reference)
//
#include <hip/hip_runtime.h>

// HIGNN edge-MLP fused kernel.
// Per edge: gather x -> d (3 or 6 floats) -> MLP d@W1+b1, relu, @W2+b2 -> 3x3
// mobility -> matvec with edge_attr -> atomicAdd into out[dst].
// Fused over hidden units: never materialize h[64]; per hh compute pre-act,
// relu, and immediately FMA into the 9 mobility accumulators.
// Weights are wave-uniform (indices depend only on loop counter) -> scalar
// loads; KPT=4 edges/thread amortizes them 4x.

constexpr int HIDDEN = 64;

template <int DIN, int KPT>
__global__ __launch_bounds__(256) void edge_mlp_kernel(
    const float* __restrict__ x,
    const int* __restrict__ edges, long long E,
    const float* __restrict__ attr,
    const float* __restrict__ W1, const float* __restrict__ b1,
    const float* __restrict__ W2, const float* __restrict__ b2,
    float* __restrict__ out)
{
    const int tid = threadIdx.x;
    const long long base = (long long)blockIdx.x * (blockDim.x * KPT) + tid;

    float d[KPT][DIN];
    float a[KPT][3];
    int   dst[KPT];
    bool  valid[KPT];

    #pragma unroll
    for (int u = 0; u < KPT; ++u) {
        long long e = base + (long long)u * blockDim.x;
        valid[u] = (e < E);
        long long ee = valid[u] ? e : 0;   // clamp: compute garbage, skip store
        if constexpr (DIN == 3) {
            // d = x[src] - x[dst]; scatter to dst (= row 1)
            int s = edges[ee];
            int t = edges[E + ee];
            dst[u] = t;
            #pragma unroll
            for (int c = 0; c < 3; ++c)
                d[u][c] = x[3 * (long long)s + c] - x[3 * (long long)t + c];
        } else {
            // 3-body: j=row0, k=row1, i=row2; d = [xk-xj, xi-xk]; scatter to i
            int j = edges[ee];
            int k = edges[E + ee];
            int i = edges[2 * E + ee];
            dst[u] = i;
            #pragma unroll
            for (int c = 0; c < 3; ++c) {
                float xj = x[3 * (long long)j + c];
                float xk = x[3 * (long long)k + c];
                float xi = x[3 * (long long)i + c];
                d[u][c]     = xk - xj;
                d[u][3 + c] = xi - xk;
            }
        }
        #pragma unroll
        for (int c = 0; c < 3; ++c) a[u][c] = attr[3 * ee + c];
    }

    // mobility accumulators, init with b2 (added pre-matvec in reference)
    float acc[KPT][9];
    #pragma unroll
    for (int u = 0; u < KPT; ++u)
        #pragma unroll
        for (int i = 0; i < 9; ++i) acc[u][i] = b2[i];

    #pragma unroll 4
    for (int hh = 0; hh < HIDDEN; ++hh) {
        const float bb = b1[hh];
        float w1r[DIN];
        #pragma unroll
        for (int r = 0; r < DIN; ++r) w1r[r] = W1[r * HIDDEN + hh];
        float w2r[9];
        #pragma unroll
        for (int i = 0; i < 9; ++i) w2r[i] = W2[hh * 9 + i];

        #pragma unroll
        for (int u = 0; u < KPT; ++u) {
            float pre = bb;
            #pragma unroll
            for (int r = 0; r < DIN; ++r) pre = fmaf(d[u][r], w1r[r], pre);
            const float h = fmaxf(pre, 0.0f);
            #pragma unroll
            for (int i = 0; i < 9; ++i) acc[u][i] = fmaf(h, w2r[i], acc[u][i]);
        }
    }

    // y = mob(3x3) @ attr(3), scatter-add
    #pragma unroll
    for (int u = 0; u < KPT; ++u) {
        if (!valid[u]) continue;
        float* o = out + 3 * (long long)dst[u];
        #pragma unroll
        for (int i = 0; i < 3; ++i) {
            float y = fmaf(acc[u][3 * i + 0], a[u][0],
                      fmaf(acc[u][3 * i + 1], a[u][1],
                           acc[u][3 * i + 2] * a[u][2]));
            atomicAdd(&o[i], y);
        }
    }
}

extern "C" void kernel_launch(void* const* d_in, const int* in_sizes, int n_in,
                              void* d_out, int out_size, void* d_ws, size_t ws_size,
                              hipStream_t stream)
{
    const float* x  = (const float*)d_in[0];
    const int*   e2 = (const int*)d_in[1];
    const int*   e3 = (const int*)d_in[2];
    const int*   es = (const int*)d_in[3];
    // d_in[4] edge_1body: unused
    const float* a2 = (const float*)d_in[5];
    const float* a3 = (const float*)d_in[6];
    const float* as = (const float*)d_in[7];
    // d_in[8] edge_attr_1body: unused
    const float* W1_2b = (const float*)d_in[9];
    const float* b1_2b = (const float*)d_in[10];
    const float* W2_2b = (const float*)d_in[11];
    const float* b2_2b = (const float*)d_in[12];
    const float* W1_3b = (const float*)d_in[13];
    const float* b1_3b = (const float*)d_in[14];
    const float* W2_3b = (const float*)d_in[15];
    const float* b2_3b = (const float*)d_in[16];
    const float* W1_s  = (const float*)d_in[17];
    const float* b1_s  = (const float*)d_in[18];
    const float* W2_s  = (const float*)d_in[19];
    const float* b2_s  = (const float*)d_in[20];

    const long long E2 = in_sizes[1] / 2;
    const long long E3 = in_sizes[2] / 3;
    const long long ES = in_sizes[3] / 2;

    float* out = (float*)d_out;
    hipMemsetAsync(out, 0, (size_t)out_size * sizeof(float), stream);

    constexpr int BLK = 256;
    constexpr int KPT = 4;
    const long long per_blk = (long long)BLK * KPT;

    int g2 = (int)((E2 + per_blk - 1) / per_blk);
    int g3 = (int)((E3 + per_blk - 1) / per_blk);
    int gs = (int)((ES + per_blk - 1) / per_blk);

    if (g2 > 0)
        edge_mlp_kernel<3, KPT><<<g2, BLK, 0, stream>>>(
            x, e2, E2, a2, W1_2b, b1_2b, W2_2b, b2_2b, out);
    if (g3 > 0)
        edge_mlp_kernel<6, KPT><<<g3, BLK, 0, stream>>>(
            x, e3, E3, a3, W1_3b, b1_3b, W2_3b, b2_3b, out);
    if (gs > 0)
        edge_mlp_kernel<3, KPT><<<gs, BLK, 0, stream>>>(
            x, es, ES, as, W1_s, b1_s, W2_s, b2_s, out);
}